// Round 4
// baseline (197.549 us; speedup 1.0000x reference)
//
#include <hip/hip_runtime.h>

typedef __attribute__((ext_vector_type(8))) unsigned short ushort8;
typedef __attribute__((ext_vector_type(8))) short short8;
typedef __attribute__((ext_vector_type(4))) float f32x4;

#define M_DIM 8192
#define N_DIM 2048
#define K_DIM 2048
#define BM 128
#define BN 128
#define BK 64

// ---- fp32 -> bf16 (RNE) ----
__device__ __forceinline__ unsigned short f32_to_bf16(float f) {
  unsigned int u = __float_as_uint(f);
  u += 0x7fffu + ((u >> 16) & 1u);
  return (unsigned short)(u >> 16);
}

__global__ void __launch_bounds__(256) cast_both_x8(
    const float* __restrict__ x, const float* __restrict__ W,
    unsigned short* __restrict__ xb, unsigned short* __restrict__ Wb) {
  const long nx = (long)M_DIM * K_DIM;
  long i = ((long)blockIdx.x * 256 + threadIdx.x) * 8;
  const float* s;
  unsigned short* d;
  if (i < nx) { s = x + i; d = xb + i; }
  else        { s = W + (i - nx); d = Wb + (i - nx); }
  float4 a = *(const float4*)(s);
  float4 b = *(const float4*)(s + 4);
  ushort8 r;
  r[0] = f32_to_bf16(a.x); r[1] = f32_to_bf16(a.y);
  r[2] = f32_to_bf16(a.z); r[3] = f32_to_bf16(a.w);
  r[4] = f32_to_bf16(b.x); r[5] = f32_to_bf16(b.y);
  r[6] = f32_to_bf16(b.z); r[7] = f32_to_bf16(b.w);
  *(ushort8*)(d) = r;
}

__device__ __forceinline__ void gload_lds16(const unsigned short* g, unsigned short* l) {
  __builtin_amdgcn_global_load_lds(
      (const __attribute__((address_space(1))) void*)g,
      (__attribute__((address_space(3))) void*)l,
      16, 0, 0);
}

// C = A(MxK) * B(NxK)^T + bias. 128x128 tile, BK=64, XOR-swizzled LDS,
// 16x16x32 MFMA (proven conflict-free: half-wave = 16 rows x 2 adjacent
// chunks -> exactly 2-way per bank. 32x32 frags force 32 rows/half-wave ->
// structural 4-way -> +4 cyc/read; do not switch back).
// LDS image: chunk p (16B) at offset p*16; chunk p holds global k-chunk
// (p&7)^(row&7) of row p>>3.
__global__ void __launch_bounds__(256) gemm_bt_bias(
    const unsigned short* __restrict__ A,
    const unsigned short* __restrict__ B,
    const float* __restrict__ bias,
    float* __restrict__ C) {
  __shared__ unsigned short sA[BM * BK];  // 16 KB
  __shared__ unsigned short sB[BN * BK];  // 16 KB

  const int tid  = threadIdx.x;
  const int lane = tid & 63;
  const int wave = tid >> 6;
  const int wm = wave & 1;
  const int wn = wave >> 1;

  // 1D grid, m-major tile order: 8 co-resident blocks per XCD share one
  // B panel + 8 A panels ~ per-XCD L2 (FETCH 139->67 MB measured)
  const int L = blockIdx.x;
  const int bm0 = (L & 63) * BM;
  const int bn0 = (L >> 6) * BN;

  // staging: 1024 chunks of 16B per matrix; thread handles p = tid + 256*j
  const unsigned short* Ag[4];
  const unsigned short* Bg[4];
  unsigned short* sAd[4];
  unsigned short* sBd[4];
#pragma unroll
  for (int j = 0; j < 4; ++j) {
    int p = tid + 256 * j;
    int r = p >> 3;
    int cbg = (p & 7) ^ (r & 7);
    Ag[j] = A + (size_t)(bm0 + r) * K_DIM + cbg * 8;
    Bg[j] = B + (size_t)(bn0 + r) * K_DIM + cbg * 8;
    sAd[j] = sA + p * 8;
    sBd[j] = sB + p * 8;
  }

  // fragment LDS offsets (loop-invariant): A[m=lane&15][k=(lane>>4)*8+j],
  // substep s adds 32 to k
  const int frow = lane & 15;
  const int q    = lane >> 4;
  int aoff[4][2], boff[4][2];
#pragma unroll
  for (int mi = 0; mi < 4; ++mi) {
    int rr = wm * 64 + mi * 16 + frow;
    int rb = rr & 7;
#pragma unroll
    for (int s = 0; s < 2; ++s) {
      int cb = s * 4 + q;
      aoff[mi][s] = (rr * 8 + (cb ^ rb)) * 8;
    }
  }
#pragma unroll
  for (int ni = 0; ni < 4; ++ni) {
    int rr = wn * 64 + ni * 16 + frow;
    int rb = rr & 7;
#pragma unroll
    for (int s = 0; s < 2; ++s) {
      int cb = s * 4 + q;
      boff[ni][s] = (rr * 8 + (cb ^ rb)) * 8;
    }
  }

  f32x4 acc[4][4] = {};

  for (int k0 = 0; k0 < K_DIM; k0 += BK) {
#pragma unroll
    for (int j = 0; j < 4; ++j) {
      gload_lds16(Ag[j] + k0, sAd[j]);
      gload_lds16(Bg[j] + k0, sBd[j]);
    }
    __syncthreads();

#pragma unroll
    for (int s = 0; s < 2; ++s) {
      short8 af[4], bf[4];
#pragma unroll
      for (int mi = 0; mi < 4; ++mi) af[mi] = *(const short8*)(sA + aoff[mi][s]);
#pragma unroll
      for (int ni = 0; ni < 4; ++ni) bf[ni] = *(const short8*)(sB + boff[ni][s]);
#pragma unroll
      for (int mi = 0; mi < 4; ++mi)
#pragma unroll
        for (int ni = 0; ni < 4; ++ni)
          acc[mi][ni] = __builtin_amdgcn_mfma_f32_16x16x32_bf16(
              af[mi], bf[ni], acc[mi][ni], 0, 0, 0);
    }
    __syncthreads();
  }

  // epilogue: C/D layout col=lane&15, row=(lane>>4)*4+reg
  const int col16 = lane & 15;
  const int row4  = (lane >> 4) * 4;
#pragma unroll
  for (int ni = 0; ni < 4; ++ni) {
    int gcol = bn0 + wn * 64 + ni * 16 + col16;
    float bv = bias[gcol];
#pragma unroll
    for (int mi = 0; mi < 4; ++mi) {
      int grow = bm0 + wm * 64 + mi * 16 + row4;
#pragma unroll
      for (int r = 0; r < 4; ++r) {
        C[(size_t)(grow + r) * N_DIM + gcol] = acc[mi][ni][r] + bv;
      }
    }
  }
}

extern "C" void kernel_launch(void* const* d_in, const int* in_sizes, int n_in,
                              void* d_out, int out_size, void* d_ws, size_t ws_size,
                              hipStream_t stream) {
  const float* x = (const float*)d_in[0];
  const float* W = (const float*)d_in[1];
  const float* b = (const float*)d_in[2];
  float* out = (float*)d_out;

  unsigned short* xb = (unsigned short*)d_ws;
  unsigned short* Wb = xb + (size_t)M_DIM * K_DIM;

  const long ntot = (long)M_DIM * K_DIM + (long)N_DIM * K_DIM;
  cast_both_x8<<<(int)(ntot / (256 * 8)), 256, 0, stream>>>(x, W, xb, Wb);

  gemm_bt_bias<<<(M_DIM / BM) * (N_DIM / BN), 256, 0, stream>>>(xb, Wb, b, out);
}

// Round 5
// 196.704 us; speedup vs baseline: 1.0043x; 1.0043x over previous
//
#include <hip/hip_runtime.h>

typedef __attribute__((ext_vector_type(8))) unsigned short ushort8;
typedef __attribute__((ext_vector_type(8))) short short8;
typedef __attribute__((ext_vector_type(4))) float f32x4;

#define M_DIM 8192
#define N_DIM 2048
#define K_DIM 2048
#define BM 128
#define BN 128
#define BK 64
#define RING 4
#define KITER (K_DIM / BK)                 // 32
#define MT_PER_BLK 4
#define NITER (KITER * MT_PER_BLK)         // 128

// ---- fp32 -> bf16 (RNE) ----
__device__ __forceinline__ unsigned short f32_to_bf16(float f) {
  unsigned int u = __float_as_uint(f);
  u += 0x7fffu + ((u >> 16) & 1u);
  return (unsigned short)(u >> 16);
}

__global__ void __launch_bounds__(256) cast_both_x8(
    const float* __restrict__ x, const float* __restrict__ W,
    unsigned short* __restrict__ xb, unsigned short* __restrict__ Wb) {
  const long nx = (long)M_DIM * K_DIM;
  long i = ((long)blockIdx.x * 256 + threadIdx.x) * 8;
  const float* s;
  unsigned short* d;
  if (i < nx) { s = x + i; d = xb + i; }
  else        { s = W + (i - nx); d = Wb + (i - nx); }
  float4 a = *(const float4*)(s);
  float4 b = *(const float4*)(s + 4);
  ushort8 r;
  r[0] = f32_to_bf16(a.x); r[1] = f32_to_bf16(a.y);
  r[2] = f32_to_bf16(a.z); r[3] = f32_to_bf16(a.w);
  r[4] = f32_to_bf16(b.x); r[5] = f32_to_bf16(b.y);
  r[6] = f32_to_bf16(b.z); r[7] = f32_to_bf16(b.w);
  *(ushort8*)(d) = r;
}

__device__ __forceinline__ void gload_lds16(const unsigned short* g, unsigned short* l) {
  __builtin_amdgcn_global_load_lds(
      (const __attribute__((address_space(1))) void*)g,
      (__attribute__((address_space(3))) void*)l,
      16, 0, 0);
}

// Producer-consumer GEMM: C = A(MxK)*B(NxK)^T + bias.
// 512 thr: waves 0-3 consume (128x128 tile, 16x16x32 MFMA, XOR-swizzled LDS),
// waves 4-7 produce (global_load_lds into 4-deep ring). No s_barrier in the
// K-loop -> no vmcnt(0) drain stall. 256 persistent blocks, 4 m-tiles each.
// LDS slot image: chunk p (16B) at p*16; holds k-chunk (p&7)^(row&7) of row p>>3.
__global__ void __launch_bounds__(512, 2) gemm_pc(
    const unsigned short* __restrict__ A,
    const unsigned short* __restrict__ B,
    const float* __restrict__ bias,
    float* __restrict__ C) {
  __shared__ unsigned short ring[RING * 2 * 8192];  // 128 KB: [slot][A|B][8192]
  __shared__ unsigned int ready[RING];
  __shared__ unsigned int done[RING];

  const int tid  = threadIdx.x;
  const int lane = tid & 63;
  const int wave = tid >> 6;

  const int blk = blockIdx.x;            // 0..255
  const int mg  = blk & 15;              // m-group: A-panel locality per XCD
  const int bn0 = (blk >> 4) * BN;       // n-tile fixed per block

  if (tid < RING) { ready[tid] = 0; done[tid] = 0; }
  __syncthreads();  // only barrier in the kernel

  if (wave >= 4) {
    // ======================= PRODUCERS (waves 4..7) =======================
    const int pw = wave - 4;
    // per-lane chunk geometry, hoisted: chunk p = lane + 64*j
    int rcA[16], rcB[16], ldoff[16];
#pragma unroll
    for (int j = 0; j < 16; ++j) {
      int p = lane + 64 * j;
      int r = p >> 3;
      int cbg = (p & 7) ^ (r & 7);
      rcA[j] = r * K_DIM + cbg * 8;      // row/chunk offset within panel
      rcB[j] = r * K_DIM + cbg * 8;
      ldoff[j] = p * 8;                  // LDS element offset within 8192
    }
    for (int t = pw; t < NITER; t += 4) {
      const int slot = t & (RING - 1);
      const int mt   = t >> 5;                   // m-tile index 0..3
      const int k0   = (t & (KITER - 1)) * BK;
      const int bm0  = (mg * MT_PER_BLK + mt) * BM;
      if (t >= RING) {
        const unsigned target = 4u * (unsigned)(t >> 2);
        while (__hip_atomic_load(&done[slot], __ATOMIC_ACQUIRE,
                                 __HIP_MEMORY_SCOPE_WORKGROUP) < target)
          __builtin_amdgcn_s_sleep(2);
      }
      unsigned short* sa = ring + slot * 16384;
      unsigned short* sb = sa + 8192;
      const unsigned short* Abase = A + (size_t)bm0 * K_DIM + k0;
      const unsigned short* Bbase = B + (size_t)bn0 * K_DIM + k0;
#pragma unroll
      for (int j = 0; j < 16; ++j) gload_lds16(Abase + rcA[j], sa + ldoff[j]);
#pragma unroll
      for (int j = 0; j < 16; ++j) gload_lds16(Bbase + rcB[j], sb + ldoff[j]);
      __builtin_amdgcn_s_waitcnt(0x0F70);  // vmcnt(0): DMA landed in LDS
      __hip_atomic_store(&ready[slot], (unsigned)(t + 1), __ATOMIC_RELEASE,
                         __HIP_MEMORY_SCOPE_WORKGROUP);
    }
  } else {
    // ======================= CONSUMERS (waves 0..3) =======================
    const int wm = wave & 1;
    const int wn = wave >> 1;
    const int frow = lane & 15;
    const int q    = lane >> 4;
    int aoff[4][2], boff[4][2];
#pragma unroll
    for (int mi = 0; mi < 4; ++mi) {
      int rr = wm * 64 + mi * 16 + frow;
      int rb = rr & 7;
#pragma unroll
      for (int s = 0; s < 2; ++s) {
        int cb = s * 4 + q;
        aoff[mi][s] = (rr * 8 + (cb ^ rb)) * 8;
      }
    }
#pragma unroll
    for (int ni = 0; ni < 4; ++ni) {
      int rr = wn * 64 + ni * 16 + frow;
      int rb = rr & 7;
#pragma unroll
      for (int s = 0; s < 2; ++s) {
        int cb = s * 4 + q;
        boff[ni][s] = (rr * 8 + (cb ^ rb)) * 8;
      }
    }
    const int col16 = lane & 15;
    const int row4  = (lane >> 4) * 4;
    float bv[4];
#pragma unroll
    for (int ni = 0; ni < 4; ++ni)
      bv[ni] = bias[bn0 + wn * 64 + ni * 16 + col16];

    f32x4 acc[4][4] = {};

    for (int t = 0; t < NITER; ++t) {
      const int slot = t & (RING - 1);
      while (__hip_atomic_load(&ready[slot], __ATOMIC_ACQUIRE,
                               __HIP_MEMORY_SCOPE_WORKGROUP) < (unsigned)(t + 1))
        __builtin_amdgcn_s_sleep(1);
      const unsigned short* sa = ring + slot * 16384;
      const unsigned short* sb = sa + 8192;
#pragma unroll
      for (int s = 0; s < 2; ++s) {
        short8 af[4], bf[4];
#pragma unroll
        for (int mi = 0; mi < 4; ++mi) af[mi] = *(const short8*)(sa + aoff[mi][s]);
#pragma unroll
        for (int ni = 0; ni < 4; ++ni) bf[ni] = *(const short8*)(sb + boff[ni][s]);
#pragma unroll
        for (int mi = 0; mi < 4; ++mi)
#pragma unroll
          for (int ni = 0; ni < 4; ++ni)
            acc[mi][ni] = __builtin_amdgcn_mfma_f32_16x16x32_bf16(
                af[mi], bf[ni], acc[mi][ni], 0, 0, 0);
      }
      if (lane == 0)
        __hip_atomic_fetch_add(&done[slot], 1u, __ATOMIC_RELEASE,
                               __HIP_MEMORY_SCOPE_WORKGROUP);
      if ((t & (KITER - 1)) == KITER - 1) {
        // epilogue for finished m-tile
        const int bm0 = (mg * MT_PER_BLK + (t >> 5)) * BM;
#pragma unroll
        for (int ni = 0; ni < 4; ++ni) {
          int gcol = bn0 + wn * 64 + ni * 16 + col16;
#pragma unroll
          for (int mi = 0; mi < 4; ++mi) {
            int grow = bm0 + wm * 64 + mi * 16 + row4;
#pragma unroll
            for (int r = 0; r < 4; ++r)
              C[(size_t)(grow + r) * N_DIM + gcol] = acc[mi][ni][r] + bv[ni];
            acc[mi][ni] = (f32x4){0.f, 0.f, 0.f, 0.f};
          }
        }
      }
    }
  }
}

extern "C" void kernel_launch(void* const* d_in, const int* in_sizes, int n_in,
                              void* d_out, int out_size, void* d_ws, size_t ws_size,
                              hipStream_t stream) {
  const float* x = (const float*)d_in[0];
  const float* W = (const float*)d_in[1];
  const float* b = (const float*)d_in[2];
  float* out = (float*)d_out;

  unsigned short* xb = (unsigned short*)d_ws;
  unsigned short* Wb = xb + (size_t)M_DIM * K_DIM;

  const long ntot = (long)M_DIM * K_DIM + (long)N_DIM * K_DIM;
  cast_both_x8<<<(int)(ntot / (256 * 8)), 256, 0, stream>>>(x, W, xb, Wb);

  gemm_pc<<<256, 512, 0, stream>>>(xb, Wb, b, out);
}